// Round 1
// baseline (166.023 us; speedup 1.0000x reference)
//
#include <hip/hip_runtime.h>
#include <stdint.h>
#include <stddef.h>

// Problem constants
#define HOUT 64
#define WOUT 64
#define CIN  32
#define COUT 16
#define BATCH 64
#define SLOC 4096          // HOUT*WOUT
#define KTOT 288           // CIN*9
#define HPAD 66            // 64 + 2 pad
// Padded-X pixel block = BATCH*CIN bf16 = 2048 ushorts = 4096 bytes

typedef __attribute__((ext_vector_type(8))) short  short8;   // 8 bf16 (4 VGPRs)
typedef __attribute__((ext_vector_type(4))) float  floatx4;  // MFMA acc / float4

// fp32 -> bf16 round-to-nearest-even (bit pattern)
static __device__ __forceinline__ unsigned short f2bf(float f) {
    union { float f; unsigned int u; } v; v.f = f;
    unsigned int u = v.u;
    unsigned int r = (u + 0x7FFFu + ((u >> 16) & 1u)) >> 16;
    return (unsigned short)r;
}

// ---------------------------------------------------------------------------
// Fused prep kernel: border-zero + X transpose + W re-layout + bias*colsum.
// 1024 blocks x 256 threads (= exactly 4 blocks/CU, machine-filling).
// All three jobs are independent -> their HBM streams overlap instead of
// running as 3 serial graph nodes (the R0 theory: serialization, not BW).
// No LDS, no barriers anywhere in this kernel.
// ---------------------------------------------------------------------------
__global__ __launch_bounds__(256, 4) void prep_kernel(const float* __restrict__ X,
                                                      const float* __restrict__ Wg,
                                                      const float* __restrict__ bias,
                                                      unsigned short* __restrict__ xt,
                                                      uint4* __restrict__ wt,
                                                      float* __restrict__ bsum) {
    const int id   = blockIdx.x;
    const int tid  = threadIdx.x;
    const int lane = tid & 63;
    const int wv   = tid >> 6;

    // ---- 1a: zero padded border of xt (260 x 4KB pixel blocks) ----
    if (id < 260) {
        int h1, w1;
        if (id < 66)       { h1 = 0;  w1 = id; }
        else if (id < 132) { h1 = 65; w1 = id - 66; }
        else { int r = id - 132; h1 = (r >> 1) + 1; w1 = (r & 1) ? 65 : 0; }
        ((uint4*)(xt + (size_t)(h1 * HPAD + w1) * 2048))[tid] = uint4{0u, 0u, 0u, 0u};
    }

    // ---- 1b: transpose X[b][c][h][w] fp32 -> xt[(h+1)][(w+1)][b][c] bf16 ----
    // 4 (h,b) units per block; per unit each thread packs 8 channels of 1 pixel.
    {
        const int w   = tid >> 2;        // 0..63
        const int cg8 = (tid & 3) * 8;   // channel group base
#pragma unroll
        for (int u = 0; u < 4; ++u) {
            const int unit = id * 4 + u;            // 0..4095
            const int h = unit >> 6, b = unit & 63;
            const float* xb = X + (((size_t)b * CIN + cg8) * HOUT + h) * WOUT + w;
            unsigned short v[8];
#pragma unroll
            for (int j = 0; j < 8; ++j)
                v[j] = f2bf(xb[(size_t)j * HOUT * WOUT]);
            uint4 pack;
            pack.x = (unsigned)v[0] | ((unsigned)v[1] << 16);
            pack.y = (unsigned)v[2] | ((unsigned)v[3] << 16);
            pack.z = (unsigned)v[4] | ((unsigned)v[5] << 16);
            pack.w = (unsigned)v[6] | ((unsigned)v[7] << 16);
            *(uint4*)(xt + (size_t)((h + 1) * HPAD + (w + 1)) * 2048 + b * CIN + cg8) = pack;
        }
    }

    // ---- 1c: W re-layout to MFMA B-fragment order + bsum. One SITE per WAVE,
    //      so the tap reduction is in-register (shfl over q only) -- the old
    //      9-wave wprep needed 2 barriers + LDS for this.
    //      Site assignment = the quarter this block id consumes in varconv
    //      (same XCD writes what it later reads -> L2/L3 locality for free).
    {
        const int lo = id & 7;
        const int q4 = (id >> 3) & 3;
        const int g  = ((id >> 5) << 3) | lo;
        const int s  = g * 16 + q4 * 4 + wv;          // bijective over 0..4095
        const int q = lane >> 4, n = lane & 15;

        const float* wb = Wg + (size_t)s * (KTOT * COUT) + (size_t)(8 * q) * 9 * COUT + n;
        float csum = 0.f;
#pragma unroll
        for (int t = 0; t < 9; ++t) {
            float w[8];
#pragma unroll
            for (int j = 0; j < 8; ++j)
                w[j] = wb[(size_t)t * COUT + (size_t)j * 9 * COUT];
            unsigned short hh[8];
#pragma unroll
            for (int j = 0; j < 8; ++j) { csum += w[j]; hh[j] = f2bf(w[j]); }
            uint4 pack;
            pack.x = (unsigned)hh[0] | ((unsigned)hh[1] << 16);
            pack.y = (unsigned)hh[2] | ((unsigned)hh[3] << 16);
            pack.z = (unsigned)hh[4] | ((unsigned)hh[5] << 16);
            pack.w = (unsigned)hh[6] | ((unsigned)hh[7] << 16);
            wt[(size_t)(s * 9 + t) * 64 + lane] = pack;
        }
        // reduce csum over q (4 lane groups) -> lanes 0..15 hold full colsum(n)
        csum += __shfl_xor(csum, 16, 64);
        csum += __shfl_xor(csum, 32, 64);
        if (lane < 16) bsum[s * COUT + n] = bias[s] * csum;
    }
}

// ---------------------------------------------------------------------------
// Main kernel. Block = 16 consecutive sites x 16 batches (quarter). Grid 1024.
// The 4 batch-quarter blocks of a site-group get ids == lo (mod 8) within a
// 32-id window -> same XCD -> Wt HBM-fetched once, 3 L2 hits.
// LDS layout: row stride 324 dwords (was 256), site stride 20 (was 16):
//   write: bank = 4*((n + q^(n&3)) % 8) + d  -> exactly 8 dwords/bank (b128 min)
//   read : c spreads 8 bank-groups, slg adds 16 -> 4-way (was 16-way).
// ---------------------------------------------------------------------------
__global__ __launch_bounds__(256, 4) void varconv_kernel(const unsigned short* __restrict__ xt,
                                                         const uint4* __restrict__ wt,
                                                         const float* __restrict__ bsum,
                                                         float* __restrict__ out) {
    __shared__ float lds[16 * 324];   // 20.25 KB; 4 blocks/CU -> 81 KB of 160

    int id = blockIdx.x;
    int lo = id & 7;                       // XCD
    int q4 = (id >> 3) & 3;                // batch quarter
    int g  = ((id >> 5) << 3) | lo;        // site-group 0..255
    int s0 = g * 16;
    int y  = s0 >> 6;
    int x0 = s0 & 63;
    int B0 = q4 * 16;

    int lane = threadIdx.x & 63, wv = threadIdx.x >> 6;
    int q = lane >> 4;          // quad
    int n = lane & 15;          // = c_out (B/D), = b-within-tile (A)

#pragma unroll
    for (int i = 0; i < 4; ++i) {
        int sl = wv * 4 + i;
        int s  = s0 + sl;
        int x  = x0 + sl;

        // --- B fragments: 9 contiguous 16B loads/lane ---
        const uint4* wf = wt + (size_t)s * 9 * 64 + lane;
        short8 bf[9];
#pragma unroll
        for (int t = 0; t < 9; ++t)
            bf[t] = *(const short8*)(wf + t * 64);

        float badd = bsum[s * COUT + n];   // bias[s]*colsum(W_s)[n]

        // --- A fragments: 9 contiguous-1KB-per-wave loads ---
        const unsigned short* ab = xt + (size_t)(B0 + n) * CIN + q * 8;
        short8 af[9];
#pragma unroll
        for (int t = 0; t < 9; ++t) {
            const int cy = t / 3, cx = t % 3;
            af[t] = *(const short8*)(ab + (size_t)((y + cy) * HPAD + (x + cx)) * 2048);
        }

        floatx4 acc = {0.f, 0.f, 0.f, 0.f};
#pragma unroll
        for (int t = 0; t < 9; ++t)
            acc = __builtin_amdgcn_mfma_f32_16x16x32_bf16(af[t], bf[t], acc, 0, 0, 0);

        // D: col = n = c_out, row(b local) = 4q+r. Slot-XOR for conflict-free b128.
        int slot = q ^ (n & 3);
        floatx4 v = {acc[0] + badd, acc[1] + badd, acc[2] + badd, acc[3] + badd};
        *(floatx4*)&lds[n * 324 + sl * 20 + slot * 4] = v;
    }

    __syncthreads();

    // --- epilogue: full-line coalesced writes (4 lanes = one 64B line) ---
    int c   = lane >> 2;     // 0..15
    int slg = lane & 3;      // 0..3
#pragma unroll
    for (int i2 = 0; i2 < 4; ++i2) {
        int ib   = wv * 4 + i2;             // local b 0..15
        int slot = (ib >> 2) ^ (c & 3);
        float o0[4];
#pragma unroll
        for (int e = 0; e < 4; ++e)
            o0[e] = lds[c * 324 + (slg * 4 + e) * 20 + slot * 4 + (ib & 3)];
        floatx4 o = {o0[0], o0[1], o0[2], o0[3]};
        *(floatx4*)(out + ((size_t)((B0 + ib) * COUT + c)) * SLOC + s0 + slg * 4) = o;
    }
}

extern "C" void kernel_launch(void* const* d_in, const int* in_sizes, int n_in,
                              void* d_out, int out_size, void* d_ws, size_t ws_size,
                              hipStream_t stream) {
    const float* X    = (const float*)d_in[0];   // [64][32][64][64] fp32
    const float* Wg   = (const float*)d_in[1];   // [4096][288][16] fp32
    const float* bias = (const float*)d_in[2];   // [4096] fp32
    float* out = (float*)d_out;                  // [64][16][4096] fp32

    // Workspace layout:
    //   xt   : 66*66*64*32*2              = 17,842,176 B
    //   wt   : 4096*9*64*16               = 37,748,736 B
    //   bsum : 4096*16*4                  =    262,144 B   (total ~53.3 MB)
    unsigned short* xt = (unsigned short*)d_ws;
    uint4* wt   = (uint4*)((char*)d_ws + 17842176);
    float* bsum = (float*)((char*)d_ws + 17842176 + 37748736);

    prep_kernel<<<1024, 256, 0, stream>>>(X, Wg, bias, xt, wt, bsum);
    varconv_kernel<<<1024, 256, 0, stream>>>(xt, wt, bsum, out);
}